// Round 1
// baseline (176.850 us; speedup 1.0000x reference)
//
#include <hip/hip_runtime.h>
#include <math.h>

// Problem constants (from setup_inputs): B=64, K=1000, NPC=256, D=768, k=16, S=10
#define BQ   64
#define KC   1000
#define NPC  256
#define DIM  768
#define TOPK 16
#define NS   10

#define NEG_INF (-__builtin_inff())

// ---------- Kernel A: normalize queries -> qn ----------
__global__ void knorm_q(const float* __restrict__ q, float* __restrict__ qn) {
    int b = blockIdx.x, t = threadIdx.x;
    const float* row = q + b * DIM;
    float v0 = row[t], v1 = row[t + 256], v2 = row[t + 512];
    __shared__ float red[256];
    red[t] = v0 * v0 + v1 * v1 + v2 * v2;
    __syncthreads();
    for (int off = 128; off; off >>= 1) {
        if (t < off) red[t] += red[t + off];
        __syncthreads();
    }
    float scale = 1.0f / fmaxf(sqrtf(red[0]), 1e-12f);
    qn[b * DIM + t]       = v0 * scale;
    qn[b * DIM + t + 256] = v1 * scale;
    qn[b * DIM + t + 512] = v2 * scale;
}

// ---------- Kernel B: cos_c[b][k] = dot(qn[b], centers[k]) / max(|centers[k]|,eps) ----------
// grid 250 blocks x 256 threads; one wave per center; center held in registers.
#define DOT12(acc, A, Bv) \
    acc = fmaf(A.x, Bv.x, acc); acc = fmaf(A.y, Bv.y, acc); \
    acc = fmaf(A.z, Bv.z, acc); acc = fmaf(A.w, Bv.w, acc);

__global__ void kcenter_scores(const float* __restrict__ qn,
                               const float* __restrict__ centers,
                               float* __restrict__ cosc) {
    int wave = threadIdx.x >> 6, lane = threadIdx.x & 63;
    int k0 = blockIdx.x * 4 + wave;            // 250*4 = 1000 exactly
    const float4* cp = (const float4*)(centers + (size_t)k0 * DIM);
    float4 c0 = cp[lane], c1 = cp[lane + 64], c2 = cp[lane + 128];
    float sq = 0.f;
    DOT12(sq, c0, c0); DOT12(sq, c1, c1); DOT12(sq, c2, c2);
    for (int off = 1; off < 64; off <<= 1) sq += __shfl_xor(sq, off);
    float inv = 1.0f / fmaxf(sqrtf(sq), 1e-12f);
    for (int b = 0; b < BQ; ++b) {
        const float4* qp = (const float4*)(qn + (size_t)b * DIM);
        float4 q0 = qp[lane], q1 = qp[lane + 64], q2 = qp[lane + 128];
        float d = 0.f;
        DOT12(d, q0, c0); DOT12(d, q1, c1); DOT12(d, q2, c2);
        for (int off = 1; off < 64; off <<= 1) d += __shfl_xor(d, off);
        if (lane == 0) cosc[b * KC + k0] = d * inv;
    }
}

// ---------- Kernel C: per-query top-NS clusters (descending, ties -> smaller idx) ----------
__global__ void ktop_clusters(const float* __restrict__ cosc, int* __restrict__ cidx) {
    int b = blockIdx.x, t = threadIdx.x;
    __shared__ float vals[1024];
    __shared__ float rv[256];
    __shared__ int   ri[256];
    for (int i = t; i < 1024; i += 256) vals[i] = (i < KC) ? cosc[b * KC + i] : NEG_INF;
    __syncthreads();
    for (int s = 0; s < NS; ++s) {
        float bv = NEG_INF; int bi = 0x7fffffff;
        for (int i = t; i < 1024; i += 256) {
            float v = vals[i];
            if (v > bv) { bv = v; bi = i; }      // increasing i -> keeps smallest idx on tie
        }
        rv[t] = bv; ri[t] = bi;
        __syncthreads();
        for (int off = 128; off; off >>= 1) {
            if (t < off) {
                float v2 = rv[t + off]; int i2 = ri[t + off];
                if (v2 > rv[t] || (v2 == rv[t] && i2 < ri[t])) { rv[t] = v2; ri[t] = i2; }
            }
            __syncthreads();
        }
        if (t == 0) { cidx[b * NS + s] = ri[0]; vals[ri[0]] = NEG_INF; }
        __syncthreads();
    }
}

// ---------- Kernel D: candidate cosines. grid = BQ*NS blocks, 256 threads ----------
__global__ void kcand(const float* __restrict__ qn, const float* __restrict__ data,
                      const int* __restrict__ cidx, float* __restrict__ cosall) {
    int bs = blockIdx.x;
    int b = bs / NS, s = bs % NS;
    int c = cidx[b * NS + s];
    int wave = threadIdx.x >> 6, lane = threadIdx.x & 63;
    const float4* qp = (const float4*)(qn + (size_t)b * DIM);
    float4 q0 = qp[lane], q1 = qp[lane + 64], q2 = qp[lane + 128];
    const float* base = data + (size_t)c * NPC * DIM;
    for (int n0 = 0; n0 < 64; ++n0) {
        int n = wave * 64 + n0;
        const float4* dp = (const float4*)(base + (size_t)n * DIM);
        float4 d0 = dp[lane], d1 = dp[lane + 64], d2 = dp[lane + 128];
        float dot = 0.f, sq = 0.f;
        DOT12(dot, q0, d0); DOT12(dot, q1, d1); DOT12(dot, q2, d2);
        DOT12(sq, d0, d0);  DOT12(sq, d1, d1);  DOT12(sq, d2, d2);
        for (int off = 1; off < 64; off <<= 1) {
            dot += __shfl_xor(dot, off);
            sq  += __shfl_xor(sq, off);
        }
        if (lane == 0)
            cosall[(size_t)b * (NS * NPC) + s * NPC + n] = dot / fmaxf(sqrtf(sq), 1e-12f);
    }
}

// ---------- Kernel E: per-query top-K over S*NPC, write ids (as float) + gather embeddings ----------
__global__ void ktop_final(const float* __restrict__ cosall, const int* __restrict__ cidx,
                           const int* __restrict__ clusted, const float* __restrict__ data,
                           float* __restrict__ out) {
    int b = blockIdx.x, t = threadIdx.x;
    __shared__ float vals[NS * NPC];
    __shared__ float rv[256];
    __shared__ int   ri[256];
    __shared__ int   docs[TOPK];
    for (int i = t; i < NS * NPC; i += 256) vals[i] = cosall[(size_t)b * (NS * NPC) + i];
    __syncthreads();
    for (int j = 0; j < TOPK; ++j) {
        float bv = NEG_INF; int bi = 0x7fffffff;
        for (int i = t; i < NS * NPC; i += 256) {
            float v = vals[i];
            if (v > bv) { bv = v; bi = i; }
        }
        rv[t] = bv; ri[t] = bi;
        __syncthreads();
        for (int off = 128; off; off >>= 1) {
            if (t < off) {
                float v2 = rv[t + off]; int i2 = ri[t + off];
                if (v2 > rv[t] || (v2 == rv[t] && i2 < ri[t])) { rv[t] = v2; ri[t] = i2; }
            }
            __syncthreads();
        }
        if (t == 0) {
            int f = ri[0];
            int s = f >> 8, n = f & (NPC - 1);
            int c = cidx[b * NS + s];
            int doc = c * NPC + n;
            docs[j] = doc;
            out[b * TOPK + j] = (float)clusted[doc];   // ids < 2^24, exact in f32
            vals[f] = NEG_INF;
        }
        __syncthreads();
    }
    // gather embeddings: raw data rows
    float* emb = out + BQ * TOPK;
    for (int j = 0; j < TOPK; ++j) {
        int doc = docs[j];
        const float4* src = (const float4*)(data + (size_t)doc * DIM);
        float4* dst = (float4*)(emb + ((size_t)(b * TOPK + j)) * DIM);
        if (t < DIM / 4) dst[t] = src[t];
    }
}

extern "C" void kernel_launch(void* const* d_in, const int* in_sizes, int n_in,
                              void* d_out, int out_size, void* d_ws, size_t ws_size,
                              hipStream_t stream) {
    const float* querys  = (const float*)d_in[0];   // (64, 768)
    const float* data    = (const float*)d_in[1];   // (1000, 256, 768)
    const float* centers = (const float*)d_in[2];   // (1000, 768)
    const int*   clusted = (const int*)d_in[3];     // (1000, 256)
    float* out = (float*)d_out;                     // [64*16 ids as float][64*16*768 emb]

    // workspace layout (floats)
    float* ws     = (float*)d_ws;
    float* qn     = ws;                              // 64*768   = 49152
    float* cosc   = qn + BQ * DIM;                   // 64*1000  = 64000
    int*   cidx   = (int*)(cosc + BQ * KC);          // 64*10    = 640
    float* cosall = (float*)(cidx + BQ * NS);        // 64*2560  = 163840

    knorm_q<<<BQ, 256, 0, stream>>>(querys, qn);
    kcenter_scores<<<KC / 4, 256, 0, stream>>>(qn, centers, cosc);
    ktop_clusters<<<BQ, 256, 0, stream>>>(cosc, cidx);
    kcand<<<BQ * NS, 256, 0, stream>>>(qn, data, cidx, cosall);
    ktop_final<<<BQ, 256, 0, stream>>>(cosall, cidx, clusted, data, out);
}

// Round 2
// 142.838 us; speedup vs baseline: 1.2381x; 1.2381x over previous
//
#include <hip/hip_runtime.h>
#include <math.h>

// Problem constants: B=64, K=1000, NPC=256, D=768, k=16, S=10
#define BQ   64
#define KC   1000
#define NPC  256
#define DIM  768
#define TOPK 16
#define NS   10

#define NEG_INF (-__builtin_inff())

#define DOT12(acc, A, Bv) \
    acc = fmaf(A.x, Bv.x, acc); acc = fmaf(A.y, Bv.y, acc); \
    acc = fmaf(A.z, Bv.z, acc); acc = fmaf(A.w, Bv.w, acc);

// ---------- Kernel A: normalize queries -> qn ----------
__global__ void knorm_q(const float* __restrict__ q, float* __restrict__ qn) {
    int b = blockIdx.x, t = threadIdx.x;
    const float* row = q + b * DIM;
    float v0 = row[t], v1 = row[t + 256], v2 = row[t + 512];
    __shared__ float red[256];
    red[t] = v0 * v0 + v1 * v1 + v2 * v2;
    __syncthreads();
    for (int off = 128; off; off >>= 1) {
        if (t < off) red[t] += red[t + off];
        __syncthreads();
    }
    float scale = 1.0f / fmaxf(sqrtf(red[0]), 1e-12f);
    qn[b * DIM + t]       = v0 * scale;
    qn[b * DIM + t + 256] = v1 * scale;
    qn[b * DIM + t + 512] = v2 * scale;
}

// ---------- Kernel B: cos_c[b][k] = dot(qn[b], centers[k]) / |centers[k]| ----------
// grid = 1000 blocks: (250 center-quads) x (4 query-groups of 16). One wave per center.
__global__ void kcenter_scores(const float* __restrict__ qn,
                               const float* __restrict__ centers,
                               float* __restrict__ cosc) {
    int wave = threadIdx.x >> 6, lane = threadIdx.x & 63;
    int cblk = blockIdx.x >> 2, qg = blockIdx.x & 3;
    int k0 = cblk * 4 + wave;                    // 250*4 = 1000 exactly
    const float4* cp = (const float4*)(centers + (size_t)k0 * DIM);
    float4 c0 = cp[lane], c1 = cp[lane + 64], c2 = cp[lane + 128];
    float sq = 0.f;
    DOT12(sq, c0, c0); DOT12(sq, c1, c1); DOT12(sq, c2, c2);
    for (int off = 1; off < 64; off <<= 1) sq += __shfl_xor(sq, off);
    float inv = 1.0f / fmaxf(sqrtf(sq), 1e-12f);
    int b0 = qg * 16;
    for (int i = 0; i < 16; i += 4) {
        const float4* qa = (const float4*)(qn + (size_t)(b0 + i + 0) * DIM);
        const float4* qb = (const float4*)(qn + (size_t)(b0 + i + 1) * DIM);
        const float4* qc = (const float4*)(qn + (size_t)(b0 + i + 2) * DIM);
        const float4* qd = (const float4*)(qn + (size_t)(b0 + i + 3) * DIM);
        float4 a0 = qa[lane], a1 = qa[lane + 64], a2 = qa[lane + 128];
        float4 e0 = qb[lane], e1 = qb[lane + 64], e2 = qb[lane + 128];
        float4 f0 = qc[lane], f1 = qc[lane + 64], f2 = qc[lane + 128];
        float4 g0 = qd[lane], g1 = qd[lane + 64], g2 = qd[lane + 128];
        float dA = 0.f, dB = 0.f, dC = 0.f, dD = 0.f;
        DOT12(dA, a0, c0); DOT12(dA, a1, c1); DOT12(dA, a2, c2);
        DOT12(dB, e0, c0); DOT12(dB, e1, c1); DOT12(dB, e2, c2);
        DOT12(dC, f0, c0); DOT12(dC, f1, c1); DOT12(dC, f2, c2);
        DOT12(dD, g0, c0); DOT12(dD, g1, c1); DOT12(dD, g2, c2);
        for (int off = 1; off < 64; off <<= 1) {
            dA += __shfl_xor(dA, off);
            dB += __shfl_xor(dB, off);
            dC += __shfl_xor(dC, off);
            dD += __shfl_xor(dD, off);
        }
        if (lane == 0) {
            cosc[(b0 + i + 0) * KC + k0] = dA * inv;
            cosc[(b0 + i + 1) * KC + k0] = dB * inv;
            cosc[(b0 + i + 2) * KC + k0] = dC * inv;
            cosc[(b0 + i + 3) * KC + k0] = dD * inv;
        }
    }
}

// ---------- block-wide argmax helper: wave shuffle reduce + cross-wave via LDS ----------
// ties -> smaller index (matches jax.lax.top_k)
__device__ __forceinline__ void wave_argmax(float& bv, int& bi) {
    for (int off = 1; off < 64; off <<= 1) {
        float v2 = __shfl_xor(bv, off);
        int   i2 = __shfl_xor(bi, off);
        if (v2 > bv || (v2 == bv && i2 < bi)) { bv = v2; bi = i2; }
    }
}

// ---------- Kernel C: per-query top-NS clusters ----------
__global__ void ktop_clusters(const float* __restrict__ cosc, int* __restrict__ cidx) {
    int b = blockIdx.x, t = threadIdx.x;
    int wave = t >> 6, lane = t & 63;
    __shared__ float vals[KC];
    __shared__ float wrv[4];
    __shared__ int   wri[4];
    for (int i = t; i < KC; i += 256) vals[i] = cosc[b * KC + i];
    __syncthreads();
    for (int s = 0; s < NS; ++s) {
        float bv = NEG_INF; int bi = 0x7fffffff;
        for (int i = t; i < KC; i += 256) {
            float v = vals[i];
            if (v > bv) { bv = v; bi = i; }
        }
        wave_argmax(bv, bi);
        if (lane == 0) { wrv[wave] = bv; wri[wave] = bi; }
        __syncthreads();
        if (t == 0) {
            float fv = wrv[0]; int fi = wri[0];
            for (int w = 1; w < 4; ++w) {
                float v2 = wrv[w]; int i2 = wri[w];
                if (v2 > fv || (v2 == fv && i2 < fi)) { fv = v2; fi = i2; }
            }
            cidx[b * NS + s] = fi;
            vals[fi] = NEG_INF;
        }
        __syncthreads();
    }
}

// ---------- Kernel D: candidate cosines ----------
// grid = BQ*NS*4 = 2560 blocks x 256 threads. Block (pair,sub) owns 64 docs of
// cluster `pair`; each wave 16 docs, 4 docs per iteration for ILP.
__global__ void kcand(const float* __restrict__ qn, const float* __restrict__ data,
                      const int* __restrict__ cidx, float* __restrict__ cosall) {
    int blk = blockIdx.x;
    int pair = blk >> 2, sub = blk & 3;
    int b = pair / NS, s = pair - b * NS;
    int c = cidx[b * NS + s];
    int wave = threadIdx.x >> 6, lane = threadIdx.x & 63;
    const float4* qp = (const float4*)(qn + (size_t)b * DIM);
    float4 q0 = qp[lane], q1 = qp[lane + 64], q2 = qp[lane + 128];
    const float* base = data + (size_t)c * NPC * DIM;
    float* outp = cosall + (size_t)pair * NPC;
    int n0 = sub * 64 + wave * 16;
    for (int it = 0; it < 4; ++it) {
        int n = n0 + it * 4;
        const float4* dpa = (const float4*)(base + (size_t)(n + 0) * DIM);
        const float4* dpb = (const float4*)(base + (size_t)(n + 1) * DIM);
        const float4* dpc = (const float4*)(base + (size_t)(n + 2) * DIM);
        const float4* dpd = (const float4*)(base + (size_t)(n + 3) * DIM);
        float4 a0 = dpa[lane], a1 = dpa[lane + 64], a2 = dpa[lane + 128];
        float4 e0 = dpb[lane], e1 = dpb[lane + 64], e2 = dpb[lane + 128];
        float4 f0 = dpc[lane], f1 = dpc[lane + 64], f2 = dpc[lane + 128];
        float4 g0 = dpd[lane], g1 = dpd[lane + 64], g2 = dpd[lane + 128];
        float dotA = 0.f, sqA = 0.f, dotB = 0.f, sqB = 0.f;
        float dotC = 0.f, sqC = 0.f, dotD = 0.f, sqD = 0.f;
        DOT12(dotA, q0, a0); DOT12(dotA, q1, a1); DOT12(dotA, q2, a2);
        DOT12(sqA,  a0, a0); DOT12(sqA,  a1, a1); DOT12(sqA,  a2, a2);
        DOT12(dotB, q0, e0); DOT12(dotB, q1, e1); DOT12(dotB, q2, e2);
        DOT12(sqB,  e0, e0); DOT12(sqB,  e1, e1); DOT12(sqB,  e2, e2);
        DOT12(dotC, q0, f0); DOT12(dotC, q1, f1); DOT12(dotC, q2, f2);
        DOT12(sqC,  f0, f0); DOT12(sqC,  f1, f1); DOT12(sqC,  f2, f2);
        DOT12(dotD, q0, g0); DOT12(dotD, q1, g1); DOT12(dotD, q2, g2);
        DOT12(sqD,  g0, g0); DOT12(sqD,  g1, g1); DOT12(sqD,  g2, g2);
        for (int off = 1; off < 64; off <<= 1) {
            dotA += __shfl_xor(dotA, off); sqA += __shfl_xor(sqA, off);
            dotB += __shfl_xor(dotB, off); sqB += __shfl_xor(sqB, off);
            dotC += __shfl_xor(dotC, off); sqC += __shfl_xor(sqC, off);
            dotD += __shfl_xor(dotD, off); sqD += __shfl_xor(sqD, off);
        }
        if (lane == 0) {
            outp[n + 0] = dotA / fmaxf(sqrtf(sqA), 1e-12f);
            outp[n + 1] = dotB / fmaxf(sqrtf(sqB), 1e-12f);
            outp[n + 2] = dotC / fmaxf(sqrtf(sqC), 1e-12f);
            outp[n + 3] = dotD / fmaxf(sqrtf(sqD), 1e-12f);
        }
    }
}

// ---------- Kernel E: per-query top-K + id write + embedding gather ----------
__global__ void ktop_final(const float* __restrict__ cosall, const int* __restrict__ cidx,
                           const int* __restrict__ clusted, const float* __restrict__ data,
                           float* __restrict__ out) {
    int b = blockIdx.x, t = threadIdx.x;
    int wave = t >> 6, lane = t & 63;
    __shared__ float vals[NS * NPC];
    __shared__ float wrv[4];
    __shared__ int   wri[4];
    __shared__ int   docs[TOPK];
    for (int i = t; i < NS * NPC; i += 256) vals[i] = cosall[(size_t)b * (NS * NPC) + i];
    __syncthreads();
    for (int j = 0; j < TOPK; ++j) {
        float bv = NEG_INF; int bi = 0x7fffffff;
        for (int i = t; i < NS * NPC; i += 256) {
            float v = vals[i];
            if (v > bv) { bv = v; bi = i; }
        }
        wave_argmax(bv, bi);
        if (lane == 0) { wrv[wave] = bv; wri[wave] = bi; }
        __syncthreads();
        if (t == 0) {
            float fv = wrv[0]; int fi = wri[0];
            for (int w = 1; w < 4; ++w) {
                float v2 = wrv[w]; int i2 = wri[w];
                if (v2 > fv || (v2 == fv && i2 < fi)) { fv = v2; fi = i2; }
            }
            int s = fi >> 8, n = fi & (NPC - 1);
            int c = cidx[b * NS + s];
            int doc = c * NPC + n;
            docs[j] = doc;
            out[b * TOPK + j] = (float)clusted[doc];   // ids < 2^24, exact in f32
            vals[fi] = NEG_INF;
        }
        __syncthreads();
    }
    // gather embeddings with all 256 threads
    float* emb = out + BQ * TOPK;
    for (int idx = t; idx < TOPK * (DIM / 4); idx += 256) {
        int j = idx / (DIM / 4), col = idx - j * (DIM / 4);
        int doc = docs[j];
        ((float4*)(emb + ((size_t)(b * TOPK + j)) * DIM))[col] =
            ((const float4*)(data + (size_t)doc * DIM))[col];
    }
}

extern "C" void kernel_launch(void* const* d_in, const int* in_sizes, int n_in,
                              void* d_out, int out_size, void* d_ws, size_t ws_size,
                              hipStream_t stream) {
    const float* querys  = (const float*)d_in[0];   // (64, 768)
    const float* data    = (const float*)d_in[1];   // (1000, 256, 768)
    const float* centers = (const float*)d_in[2];   // (1000, 768)
    const int*   clusted = (const int*)d_in[3];     // (1000, 256)
    float* out = (float*)d_out;                     // [64*16 ids as float][64*16*768 emb]

    float* ws     = (float*)d_ws;
    float* qn     = ws;                              // 64*768
    float* cosc   = qn + BQ * DIM;                   // 64*1000
    int*   cidx   = (int*)(cosc + BQ * KC);          // 64*10
    float* cosall = (float*)(cidx + BQ * NS);        // 64*2560

    knorm_q<<<BQ, 256, 0, stream>>>(querys, qn);
    kcenter_scores<<<KC, 256, 0, stream>>>(qn, centers, cosc);
    ktop_clusters<<<BQ, 256, 0, stream>>>(cosc, cidx);
    kcand<<<BQ * NS * 4, 256, 0, stream>>>(qn, data, cidx, cosall);
    ktop_final<<<BQ, 256, 0, stream>>>(cosall, cidx, clusted, data, out);
}